// Round 9
// baseline (466.792 us; speedup 1.0000x reference)
//
#include <hip/hip_runtime.h>
#include <stdint.h>

#define V_ITEMS 100000
#define EDIM    128
#define BATCH   4096
#define HLEN    50
#define TOPK    21

#define MT      64                      // batches per block in K2
#define MS      4                       // 16-row MFMA sub-blocks (MT/16)
#define VSPLIT  4                       // item-range splits (R4-proven overhead level)
#define NWAVE   12                      // waves per block (768 thr) -> 3 waves/SIMD
#define NCHUNK_TOT (V_ITEMS / 16)       // 6250 16-item chunks total
#define NITER   132                     // ceil(1563/12)=131 -> 132 (even)
#define CAP2    256                     // per-batch candidate capacity (R4-proven)
#define NKEEP   32                      // superset kept per (batch, range)
#define NCAND   (NKEEP * VSPLIT)        // 128 candidates per batch into K3

typedef __attribute__((ext_vector_type(8))) short          bf16x8;
typedef __attribute__((ext_vector_type(4))) float          f32x4;
typedef __attribute__((ext_vector_type(8))) unsigned short u16x8;

__device__ inline unsigned short f2bf(float x) {           // RNE fp32->bf16
    unsigned u = __float_as_uint(x);
    return (unsigned short)((u + 0x7FFFu + ((u >> 16) & 1u)) >> 16);
}

// ---------------- K0: emb fp32 -> bf16 table in ws --------------------------
__global__ __launch_bounds__(256) void conv_bf16(
        const float* __restrict__ s, unsigned short* __restrict__ d) {
    size_t i = (size_t)blockIdx.x * 256 + threadIdx.x;     // 8 floats/thread
    const float4* sp = (const float4*)s + i * 2;
    float4 a = sp[0], b = sp[1];
    u16x8 o;
    o[0] = f2bf(a.x); o[1] = f2bf(a.y); o[2] = f2bf(a.z); o[3] = f2bf(a.w);
    o[4] = f2bf(b.x); o[5] = f2bf(b.y); o[6] = f2bf(b.z); o[7] = f2bf(b.w);
    *((u16x8*)d + i) = o;
}

// ---------------- K1: masked mean-pool queries -> bf16 + fp32 ---------------
__global__ __launch_bounds__(EDIM) void query_bf16(
        const int* __restrict__ seq, const int* __restrict__ len,
        const float* __restrict__ emb, unsigned short* __restrict__ qbf,
        float* __restrict__ qf) {
    int b = blockIdx.x, d = threadIdx.x;
    int n = len[b];
    float s = 0.f;
    for (int l = 0; l < n; l++)
        s += emb[(size_t)seq[b * HLEN + l] * EDIM + d];
    float q = s / (float)(n > 0 ? n : 1);
    qbf[b * EDIM + d] = f2bf(q);
    qf [b * EDIM + d] = q;
}

// ---- exact top-32 of a batch's candidate buffer: ballot-bisection on keys --
// CAP2 = 256 -> 4 elements per lane (verbatim from the R4-passing kernel).
__device__ inline void compact_batch(float* cv, int* ci, int* cnt, float* thr,
                                     int b, int lane) {
    int n = min(cnt[b], CAP2);
    float val[4]; int idx[4]; unsigned key[4];
    #pragma unroll
    for (int e = 0; e < 4; e++) {
        int i = lane + e * 64;
        if (i < n) {
            float v = cv[b * CAP2 + i];
            unsigned u = __float_as_uint(v);
            key[e] = (u & 0x80000000u) ? ~u : (u | 0x80000000u);
            val[e] = v; idx[e] = ci[b * CAP2 + i];
        } else { key[e] = 0u; val[e] = 0.f; idx[e] = 0; }
    }
    unsigned cur = 0u;                 // max T with count(key >= T) >= 32
    #pragma unroll 1
    for (int bit = 31; bit >= 0; bit--) {
        unsigned mid = cur | (1u << bit);
        int c = 0;
        #pragma unroll
        for (int e = 0; e < 4; e++)
            c += __popcll(__ballot(key[e] >= mid));
        if (c >= NKEEP) cur = mid;
    }
    int base = 0;                      // ballot prefix-sum compaction, no atomics
    #pragma unroll
    for (int e = 0; e < 4; e++) {
        bool keep = key[e] >= cur;
        unsigned long long m = __ballot(keep);
        int p = base + (int)__popcll(m & ((1ull << lane) - 1ull));
        if (keep && p < NKEEP) { cv[b * CAP2 + p] = val[e]; ci[b * CAP2 + p] = idx[e]; }
        base += (int)__popcll(m);
    }
    if (lane == 0) {
        cnt[b] = NKEEP;
        thr[b] = (cur & 0x80000000u) ? __uint_as_float(cur ^ 0x80000000u)
                                     : __uint_as_float(~cur);
    }
}

// ---------------- K2: bf16-MFMA scoring + fused per-range top-32 ------------
// grid = 64 batch-groups x 4 V-ranges = 256 blocks (1/CU, single tranche),
// 768 threads = 12 waves = 3 waves/SIMD (LDS 131.6KB caps at 1 block/CU).
//
// R8 post-mortem: NWAVE=12 on the R4 algorithm = 355->315us (PASS). But
// VGPR_Count=80 proves the B double-buffer was dead: afr alone is 64 regs,
// so the scheduler SANK the prefetch loads to their use -> every wave-iter
// serially eats ~200cy of L2-hit latency before its MFMAs (issue util 35%).
// This round's single change: __builtin_amdgcn_sched_barrier(0) after the
// prefetch-issue block pins the loads above the MFMA+insert phase, keeping
// them in flight across ~600 issue-cycles; the wait for `cur` (issued one
// full iteration earlier) becomes a counted-vmcnt no-op. Scheduling-only
// change: semantics identical to the R8-passing kernel. Diagnostic: VGPR
// should rise to ~115-130; if it stays 80 the barrier failed.
__global__ __launch_bounds__(768, 3) void score_topk(
        const unsigned short* __restrict__ qbf,
        const unsigned short* __restrict__ ebf,
        int* __restrict__ candOut) {
    __shared__ float cv[MT * CAP2];    // 64 KB
    __shared__ int   ci[MT * CAP2];    // 64 KB
    __shared__ int   cnt[MT];
    __shared__ float thr[MT];

    const int tid  = threadIdx.x;
    const int lane = tid & 63;
    const int w    = tid >> 6;                       // wave 0..11
    const int r    = blockIdx.x & (VSPLIT - 1);      // V-range
    const int mg   = blockIdx.x / VSPLIT;            // batch group
    const int b0   = mg * MT;
    const int n15  = lane & 15, quad = lane >> 4;

    const int cstart = (r * NCHUNK_TOT) / VSPLIT;
    const int nch    = ((r + 1) * NCHUNK_TOT) / VSPLIT - cstart;  // 1562/1563

    if (tid < MT) { cnt[tid] = 0; thr[tid] = -INFINITY; }
    __syncthreads();

    // resident A-fragments: 4 msubs x 4 K-steps (64 VGPRs)
    bf16x8 afr[MS][4];
    #pragma unroll
    for (int ms = 0; ms < MS; ms++)
        #pragma unroll
        for (int t = 0; t < 4; t++)
            afr[ms][t] = *(const bf16x8*)(qbf + (b0 + ms * 16 + n15) * EDIM
                                          + t * 32 + quad * 8);
    float thrR[MS * 4];
    #pragma unroll
    for (int i = 0; i < MS * 4; i++) thrR[i] = -INFINITY;

    const unsigned short* bbase = ebf + ((size_t)cstart * 16 + n15) * EDIM + quad * 8;

    int nextEvt = 1;

    // one iteration: MFMA+insert on `cur`, prefetch chunk(iter+1) into `nxt`
    auto body = [&](int iter, bf16x8 (&cur)[4], bf16x8 (&nxt)[4]) {
        {   // prefetch next iteration's B fragments
            int nit   = (iter + 1 < NITER) ? (iter + 1) : iter;
            int pch   = nit * NWAVE + w;
            int pcc   = (pch < nch) ? pch : (nch - 1);
            const unsigned short* bp = bbase + (size_t)pcc * (16 * EDIM);
            #pragma unroll
            for (int t = 0; t < 4; t++) nxt[t] = *(const bf16x8*)(bp + t * 32);
        }
        // pin: prefetch loads may not sink below this point -> they stay in
        // flight across the MFMA + insert phase (the whole point of dbuf).
        __builtin_amdgcn_sched_barrier(0);

        f32x4 acc[MS];
        #pragma unroll
        for (int ms = 0; ms < MS; ms++) acc[ms] = (f32x4){0.f, 0.f, 0.f, 0.f};
        #pragma unroll
        for (int t = 0; t < 4; t++)
            #pragma unroll
            for (int ms = 0; ms < MS; ms++)
                acc[ms] = __builtin_amdgcn_mfma_f32_16x16x32_bf16(afr[ms][t], cur[t], acc[ms], 0, 0, 0);

        int chunk = iter * NWAVE + w;
        bool act  = chunk < nch;                     // wave-uniform
        // C/D: item n = lane&15 (col), batch row = quad*4 + reg  [m89/m91]
        if (act) {
            int item = (cstart + chunk) * 16 + n15;
            float s[MS * 4]; bool hit = false;
            #pragma unroll
            for (int k = 0; k < MS * 4; k++) {
                float v = acc[k >> 2][k & 3];
                s[k] = v;
                hit |= (v > thrR[k]);
            }
            if (__any(hit)) {                        // wave-uniform slow path
                #pragma unroll
                for (int k = 0; k < MS * 4; k++) {
                    if (s[k] > thrR[k]) {
                        int row = (k >> 2) * 16 + (quad << 2) + (k & 3);
                        int pz = atomicAdd(&cnt[row], 1);
                        if (pz < CAP2) { cv[row * CAP2 + pz] = s[k]; ci[row * CAP2 + pz] = item; }
                    }
                }
            }
        }
        // static compaction schedule: iters 1,2,4,...,128, and the final iter.
        // Uniform across waves -> barrier counts always match. Trigger cnt>96
        // with CAP2=256: R4-proven headroom.
        if (iter + 1 == nextEvt || iter + 1 == NITER) {
            if (iter + 1 == nextEvt) nextEvt <<= 1;
            bool fin = (iter + 1 == NITER);
            __syncthreads();
            #pragma unroll 1
            for (int b = w; b < MT; b += NWAVE) {    // rows striped over 12 waves
                if (fin || cnt[b] > 96) compact_batch(cv, ci, cnt, thr, b, lane);
            }
            __syncthreads();
            #pragma unroll
            for (int ms = 0; ms < MS; ms++)
                #pragma unroll
                for (int rr = 0; rr < 4; rr++)
                    thrR[ms * 4 + rr] = thr[ms * 16 + (quad << 2) + rr];
        }
    };

    bf16x8 bA[4], bB[4];
    {   // preload iter 0
        int cc0 = (w < nch) ? w : (nch - 1);
        const unsigned short* bp = bbase + (size_t)cc0 * (16 * EDIM);
        #pragma unroll
        for (int t = 0; t < 4; t++) bA[t] = *(const bf16x8*)(bp + t * 32);
    }
    for (int iter = 0; iter < NITER; iter += 2) {    // NITER even: no tail
        body(iter,     bA, bB);
        body(iter + 1, bB, bA);
    }

    // final compact guaranteed cnt==32 per batch; emit candidate indices
    for (int b = w; b < MT; b += NWAVE) {
        if (lane < NKEEP)
            candOut[(b0 + b) * NCAND + r * NKEEP + lane] = ci[b * CAP2 + lane];
    }
}

// ---------------- K3: fp64 rescore of 128 candidates, exact top-21 ----------
__global__ __launch_bounds__(256) void rescore(
        const float* __restrict__ qf, const float* __restrict__ emb,
        const int* __restrict__ cand, float* __restrict__ out) {
    __shared__ double qd[EDIM];
    __shared__ double sv[NCAND];
    __shared__ int    si[NCAND];
    int b = blockIdx.x, t = threadIdx.x;
    if (t < EDIM) qd[t] = (double)qf[b * EDIM + t];  // precomputed in K1
    __syncthreads();

    int c = t >> 1, h = t & 1;                       // 2 threads per candidate
    int idx = cand[b * NCAND + c];
    const float4* ev = (const float4*)(emb + (size_t)idx * EDIM + h * 64);
    double part = 0.0;
    #pragma unroll 4
    for (int j = 0; j < 16; j++) {
        float4 e = ev[j];
        int d = h * 64 + j * 4;
        part += qd[d] * (double)e.x + qd[d + 1] * (double)e.y
              + qd[d + 2] * (double)e.z + qd[d + 3] * (double)e.w;
    }
    part += __shfl_xor(part, 1);                     // combine halves
    if (h == 0) { sv[c] = part; si[c] = idx; }
    __syncthreads();

    if (t < NCAND) {                                 // rank among 128 (ties: low idx)
        double v = sv[t]; int id = si[t];
        int rank = 0;
        for (int j = 0; j < NCAND; j++) {
            double vj = sv[j]; int ij = si[j];
            rank += (vj > v || (vj == v && ij < id)) ? 1 : 0;
        }
        if (rank < TOPK) {
            out[(size_t)b * TOPK + rank] = (float)v;
            out[(size_t)BATCH * TOPK + (size_t)b * TOPK + rank] = (float)id;
        }
    }
}

extern "C" void kernel_launch(void* const* d_in, const int* in_sizes, int n_in,
                              void* d_out, int out_size, void* d_ws, size_t ws_size,
                              hipStream_t stream) {
    const int*   seq = (const int*)d_in[0];
    const int*   len = (const int*)d_in[1];
    const float* emb = (const float*)d_in[2];
    float* out = (float*)d_out;

    // ws: q_bf [4096*128 u16] | emb_bf [100000*128 u16] | cand [4096*128 i32]
    //     | q_f32 [4096*128 f32]   (~30.6 MB total)
    unsigned short* qbf  = (unsigned short*)d_ws;
    unsigned short* ebf  = qbf + (size_t)BATCH * EDIM;
    int*            cand = (int*)(ebf + (size_t)V_ITEMS * EDIM);
    float*          qf   = (float*)(cand + (size_t)BATCH * NCAND);

    conv_bf16 <<<(V_ITEMS * EDIM) / (256 * 8), 256, 0, stream>>>(emb, ebf);
    query_bf16<<<BATCH, EDIM, 0, stream>>>(seq, len, emb, qbf, qf);
    score_topk<<<(BATCH / MT) * VSPLIT, 768, 0, stream>>>(qbf, ebf, cand);
    rescore   <<<BATCH, 256, 0, stream>>>(qf, emb, cand, out);
}

// Round 10
// 455.640 us; speedup vs baseline: 1.0245x; 1.0245x over previous
//
#include <hip/hip_runtime.h>
#include <stdint.h>

#define V_ITEMS 100000
#define EDIM    128
#define BATCH   4096
#define HLEN    50
#define TOPK    21

#define MT      64                      // batches per block in K2
#define MS      4                       // 16-row MFMA sub-blocks (MT/16)
#define VSPLIT  4                       // item-range splits (R4-proven overhead level)
#define NWAVE   12                      // waves per block (768 thr) -> 3 waves/SIMD
#define NCHUNK_TOT (V_ITEMS / 16)       // 6250 16-item chunks total
#define NITER   132                     // ceil(1563/12)=131 -> 132 (even)
#define CAP2    256                     // per-batch candidate capacity (R4-proven)
#define NKEEP   32                      // superset kept per (batch, range)
#define NCAND   (NKEEP * VSPLIT)        // 128 candidates per batch into K3

typedef __attribute__((ext_vector_type(8))) short          bf16x8;
typedef __attribute__((ext_vector_type(4))) float          f32x4;
typedef __attribute__((ext_vector_type(8))) unsigned short u16x8;

__device__ inline unsigned short f2bf(float x) {           // RNE fp32->bf16
    unsigned u = __float_as_uint(x);
    return (unsigned short)((u + 0x7FFFu + ((u >> 16) & 1u)) >> 16);
}

// ---------------- K0: emb fp32 -> bf16 table in ws --------------------------
__global__ __launch_bounds__(256) void conv_bf16(
        const float* __restrict__ s, unsigned short* __restrict__ d) {
    size_t i = (size_t)blockIdx.x * 256 + threadIdx.x;     // 8 floats/thread
    const float4* sp = (const float4*)s + i * 2;
    float4 a = sp[0], b = sp[1];
    u16x8 o;
    o[0] = f2bf(a.x); o[1] = f2bf(a.y); o[2] = f2bf(a.z); o[3] = f2bf(a.w);
    o[4] = f2bf(b.x); o[5] = f2bf(b.y); o[6] = f2bf(b.z); o[7] = f2bf(b.w);
    *((u16x8*)d + i) = o;
}

// ---------------- K1: masked mean-pool queries -> bf16 + fp32 ---------------
__global__ __launch_bounds__(EDIM) void query_bf16(
        const int* __restrict__ seq, const int* __restrict__ len,
        const float* __restrict__ emb, unsigned short* __restrict__ qbf,
        float* __restrict__ qf) {
    int b = blockIdx.x, d = threadIdx.x;
    int n = len[b];
    float s = 0.f;
    for (int l = 0; l < n; l++)
        s += emb[(size_t)seq[b * HLEN + l] * EDIM + d];
    float q = s / (float)(n > 0 ? n : 1);
    qbf[b * EDIM + d] = f2bf(q);
    qf [b * EDIM + d] = q;
}

// ---- exact top-32 of a batch's candidate buffer: ballot-bisection on keys --
// CAP2 = 256 -> 4 elements per lane (verbatim from the R4-passing kernel).
__device__ inline void compact_batch(float* cv, int* ci, int* cnt, float* thr,
                                     int b, int lane) {
    int n = min(cnt[b], CAP2);
    float val[4]; int idx[4]; unsigned key[4];
    #pragma unroll
    for (int e = 0; e < 4; e++) {
        int i = lane + e * 64;
        if (i < n) {
            float v = cv[b * CAP2 + i];
            unsigned u = __float_as_uint(v);
            key[e] = (u & 0x80000000u) ? ~u : (u | 0x80000000u);
            val[e] = v; idx[e] = ci[b * CAP2 + i];
        } else { key[e] = 0u; val[e] = 0.f; idx[e] = 0; }
    }
    unsigned cur = 0u;                 // max T with count(key >= T) >= 32
    #pragma unroll 1
    for (int bit = 31; bit >= 0; bit--) {
        unsigned mid = cur | (1u << bit);
        int c = 0;
        #pragma unroll
        for (int e = 0; e < 4; e++)
            c += __popcll(__ballot(key[e] >= mid));
        if (c >= NKEEP) cur = mid;
    }
    int base = 0;                      // ballot prefix-sum compaction, no atomics
    #pragma unroll
    for (int e = 0; e < 4; e++) {
        bool keep = key[e] >= cur;
        unsigned long long m = __ballot(keep);
        int p = base + (int)__popcll(m & ((1ull << lane) - 1ull));
        if (keep && p < NKEEP) { cv[b * CAP2 + p] = val[e]; ci[b * CAP2 + p] = idx[e]; }
        base += (int)__popcll(m);
    }
    if (lane == 0) {
        cnt[b] = NKEEP;
        thr[b] = (cur & 0x80000000u) ? __uint_as_float(cur ^ 0x80000000u)
                                     : __uint_as_float(~cur);
    }
}

// ---------------- K2: bf16-MFMA scoring + fused per-range top-32 ------------
// grid = 64 batch-groups x 4 V-ranges = 256 blocks (1/CU, single tranche),
// 768 threads = 12 waves = 3 waves/SIMD (LDS 131.6KB caps at 1 block/CU).
//
// R9 post-mortem: sched_barrier after prefetch = null (loads were never the
// exposed latency; compiler emits counted vmcnt). Cycle model: 1909 cy per
// wave-iter vs ~350 cy of issue -> ~1500 cy exposed latency. Attribution:
// ~7 of 16 divergent insert blocks taken per iter, each a serial
// ds_atomic_add_rtn -> lgkmcnt(0) -> store chain (~140 cy) because pz is
// consumed immediately. THIS round: two-pass insert -- pass 1 issues all
// passing atomics back-to-back into pz[k] (no intervening waits), pass 2
// waits once (counted lgkm) and does the guarded stores. Semantics are
// bit-identical to the R4/R8-proven insert (same atomics, slot reservation
// order-independent); only the latency structure changes: 7x140 -> 1x140.
__global__ __launch_bounds__(768, 3) void score_topk(
        const unsigned short* __restrict__ qbf,
        const unsigned short* __restrict__ ebf,
        int* __restrict__ candOut) {
    __shared__ float cv[MT * CAP2];    // 64 KB
    __shared__ int   ci[MT * CAP2];    // 64 KB
    __shared__ int   cnt[MT];
    __shared__ float thr[MT];

    const int tid  = threadIdx.x;
    const int lane = tid & 63;
    const int w    = tid >> 6;                       // wave 0..11
    const int r    = blockIdx.x & (VSPLIT - 1);      // V-range
    const int mg   = blockIdx.x / VSPLIT;            // batch group
    const int b0   = mg * MT;
    const int n15  = lane & 15, quad = lane >> 4;

    const int cstart = (r * NCHUNK_TOT) / VSPLIT;
    const int nch    = ((r + 1) * NCHUNK_TOT) / VSPLIT - cstart;  // 1562/1563

    if (tid < MT) { cnt[tid] = 0; thr[tid] = -INFINITY; }
    __syncthreads();

    // resident A-fragments: 4 msubs x 4 K-steps (64 VGPRs)
    bf16x8 afr[MS][4];
    #pragma unroll
    for (int ms = 0; ms < MS; ms++)
        #pragma unroll
        for (int t = 0; t < 4; t++)
            afr[ms][t] = *(const bf16x8*)(qbf + (b0 + ms * 16 + n15) * EDIM
                                          + t * 32 + quad * 8);
    float thrR[MS * 4];
    #pragma unroll
    for (int i = 0; i < MS * 4; i++) thrR[i] = -INFINITY;

    const unsigned short* bbase = ebf + ((size_t)cstart * 16 + n15) * EDIM + quad * 8;

    int nextEvt = 1;

    // one iteration: MFMA+insert on `cur`, prefetch chunk(iter+1) into `nxt`
    auto body = [&](int iter, bf16x8 (&cur)[4], bf16x8 (&nxt)[4]) {
        {   // prefetch next iteration's B fragments
            int nit   = (iter + 1 < NITER) ? (iter + 1) : iter;
            int pch   = nit * NWAVE + w;
            int pcc   = (pch < nch) ? pch : (nch - 1);
            const unsigned short* bp = bbase + (size_t)pcc * (16 * EDIM);
            #pragma unroll
            for (int t = 0; t < 4; t++) nxt[t] = *(const bf16x8*)(bp + t * 32);
        }
        f32x4 acc[MS];
        #pragma unroll
        for (int ms = 0; ms < MS; ms++) acc[ms] = (f32x4){0.f, 0.f, 0.f, 0.f};
        #pragma unroll
        for (int t = 0; t < 4; t++)
            #pragma unroll
            for (int ms = 0; ms < MS; ms++)
                acc[ms] = __builtin_amdgcn_mfma_f32_16x16x32_bf16(afr[ms][t], cur[t], acc[ms], 0, 0, 0);

        int chunk = iter * NWAVE + w;
        bool act  = chunk < nch;                     // wave-uniform
        // C/D: item n = lane&15 (col), batch row = quad*4 + reg  [m89/m91]
        if (act) {
            int item = (cstart + chunk) * 16 + n15;
            float s[MS * 4]; bool pass[MS * 4]; bool hit = false;
            #pragma unroll
            for (int k = 0; k < MS * 4; k++) {
                float v = acc[k >> 2][k & 3];
                s[k] = v;
                pass[k] = (v > thrR[k]);
                hit |= pass[k];
            }
            if (__any(hit)) {                        // wave-uniform slow path
                int pz[MS * 4];
                // pass 1: issue all slot-reserving atomics, no waits between
                #pragma unroll
                for (int k = 0; k < MS * 4; k++) {
                    if (pass[k]) {
                        int row = (k >> 2) * 16 + (quad << 2) + (k & 3);
                        pz[k] = atomicAdd(&cnt[row], 1);
                    }
                }
                // keep all atomics above all stores so their latencies overlap
                __builtin_amdgcn_sched_barrier(0);
                // pass 2: one coalesced counted-lgkm wait, then stores
                #pragma unroll
                for (int k = 0; k < MS * 4; k++) {
                    if (pass[k] && pz[k] < CAP2) {
                        int row = (k >> 2) * 16 + (quad << 2) + (k & 3);
                        cv[row * CAP2 + pz[k]] = s[k];
                        ci[row * CAP2 + pz[k]] = item;
                    }
                }
            }
        }
        // static compaction schedule: iters 1,2,4,...,128, and the final iter.
        // Uniform across waves -> barrier counts always match. Trigger cnt>96
        // with CAP2=256: R4-proven headroom.
        if (iter + 1 == nextEvt || iter + 1 == NITER) {
            if (iter + 1 == nextEvt) nextEvt <<= 1;
            bool fin = (iter + 1 == NITER);
            __syncthreads();
            #pragma unroll 1
            for (int b = w; b < MT; b += NWAVE) {    // rows striped over 12 waves
                if (fin || cnt[b] > 96) compact_batch(cv, ci, cnt, thr, b, lane);
            }
            __syncthreads();
            #pragma unroll
            for (int ms = 0; ms < MS; ms++)
                #pragma unroll
                for (int rr = 0; rr < 4; rr++)
                    thrR[ms * 4 + rr] = thr[ms * 16 + (quad << 2) + rr];
        }
    };

    bf16x8 bA[4], bB[4];
    {   // preload iter 0
        int cc0 = (w < nch) ? w : (nch - 1);
        const unsigned short* bp = bbase + (size_t)cc0 * (16 * EDIM);
        #pragma unroll
        for (int t = 0; t < 4; t++) bA[t] = *(const bf16x8*)(bp + t * 32);
    }
    for (int iter = 0; iter < NITER; iter += 2) {    // NITER even: no tail
        body(iter,     bA, bB);
        body(iter + 1, bB, bA);
    }

    // final compact guaranteed cnt==32 per batch; emit candidate indices
    for (int b = w; b < MT; b += NWAVE) {
        if (lane < NKEEP)
            candOut[(b0 + b) * NCAND + r * NKEEP + lane] = ci[b * CAP2 + lane];
    }
}

// ---------------- K3: fp64 rescore of 128 candidates, exact top-21 ----------
__global__ __launch_bounds__(256) void rescore(
        const float* __restrict__ qf, const float* __restrict__ emb,
        const int* __restrict__ cand, float* __restrict__ out) {
    __shared__ double qd[EDIM];
    __shared__ double sv[NCAND];
    __shared__ int    si[NCAND];
    int b = blockIdx.x, t = threadIdx.x;
    if (t < EDIM) qd[t] = (double)qf[b * EDIM + t];  // precomputed in K1
    __syncthreads();

    int c = t >> 1, h = t & 1;                       // 2 threads per candidate
    int idx = cand[b * NCAND + c];
    const float4* ev = (const float4*)(emb + (size_t)idx * EDIM + h * 64);
    double part = 0.0;
    #pragma unroll 4
    for (int j = 0; j < 16; j++) {
        float4 e = ev[j];
        int d = h * 64 + j * 4;
        part += qd[d] * (double)e.x + qd[d + 1] * (double)e.y
              + qd[d + 2] * (double)e.z + qd[d + 3] * (double)e.w;
    }
    part += __shfl_xor(part, 1);                     // combine halves
    if (h == 0) { sv[c] = part; si[c] = idx; }
    __syncthreads();

    if (t < NCAND) {                                 // rank among 128 (ties: low idx)
        double v = sv[t]; int id = si[t];
        int rank = 0;
        for (int j = 0; j < NCAND; j++) {
            double vj = sv[j]; int ij = si[j];
            rank += (vj > v || (vj == v && ij < id)) ? 1 : 0;
        }
        if (rank < TOPK) {
            out[(size_t)b * TOPK + rank] = (float)v;
            out[(size_t)BATCH * TOPK + (size_t)b * TOPK + rank] = (float)id;
        }
    }
}

extern "C" void kernel_launch(void* const* d_in, const int* in_sizes, int n_in,
                              void* d_out, int out_size, void* d_ws, size_t ws_size,
                              hipStream_t stream) {
    const int*   seq = (const int*)d_in[0];
    const int*   len = (const int*)d_in[1];
    const float* emb = (const float*)d_in[2];
    float* out = (float*)d_out;

    // ws: q_bf [4096*128 u16] | emb_bf [100000*128 u16] | cand [4096*128 i32]
    //     | q_f32 [4096*128 f32]   (~30.6 MB total)
    unsigned short* qbf  = (unsigned short*)d_ws;
    unsigned short* ebf  = qbf + (size_t)BATCH * EDIM;
    int*            cand = (int*)(ebf + (size_t)V_ITEMS * EDIM);
    float*          qf   = (float*)(cand + (size_t)BATCH * NCAND);

    conv_bf16 <<<(V_ITEMS * EDIM) / (256 * 8), 256, 0, stream>>>(emb, ebf);
    query_bf16<<<BATCH, EDIM, 0, stream>>>(seq, len, emb, qbf, qf);
    score_topk<<<(BATCH / MT) * VSPLIT, 768, 0, stream>>>(qbf, ebf, cand);
    rescore   <<<BATCH, 256, 0, stream>>>(qf, emb, cand, out);
}

// Round 12
// 455.210 us; speedup vs baseline: 1.0254x; 1.0009x over previous
//
#include <hip/hip_runtime.h>
#include <stdint.h>

#define V_ITEMS 100000
#define EDIM    128
#define BATCH   4096
#define HLEN    50
#define TOPK    21

#define MT      64                      // batches per block in K2
#define MS      4                       // 16-row MFMA sub-blocks (MT/16)
#define VSPLIT  4                       // item-range splits (R4-proven overhead level)
#define NWAVE   12                      // waves per block (768 thr) -> 3 waves/SIMD
#define NCHUNK_TOT (V_ITEMS / 16)       // 6250 16-item chunks total
#define NITER   132                     // ceil(1563/12)=131 -> 132 (even)
#define CAP2    256                     // per-batch candidate capacity (R4-proven)
#define NKEEP   32                      // superset kept per (batch, range)
#define NCAND   (NKEEP * VSPLIT)        // 128 candidates per batch into K3

typedef __attribute__((ext_vector_type(8))) short          bf16x8;
typedef __attribute__((ext_vector_type(4))) float          f32x4;
typedef __attribute__((ext_vector_type(8))) unsigned short u16x8;

__device__ inline unsigned short f2bf(float x) {           // RNE fp32->bf16
    unsigned u = __float_as_uint(x);
    return (unsigned short)((u + 0x7FFFu + ((u >> 16) & 1u)) >> 16);
}

// ---------------- K0: emb fp32 -> bf16 table in ws --------------------------
__global__ __launch_bounds__(256) void conv_bf16(
        const float* __restrict__ s, unsigned short* __restrict__ d) {
    size_t i = (size_t)blockIdx.x * 256 + threadIdx.x;     // 8 floats/thread
    const float4* sp = (const float4*)s + i * 2;
    float4 a = sp[0], b = sp[1];
    u16x8 o;
    o[0] = f2bf(a.x); o[1] = f2bf(a.y); o[2] = f2bf(a.z); o[3] = f2bf(a.w);
    o[4] = f2bf(b.x); o[5] = f2bf(b.y); o[6] = f2bf(b.z); o[7] = f2bf(b.w);
    *((u16x8*)d + i) = o;
}

// ---------------- K1: masked mean-pool queries -> bf16 + fp32 ---------------
__global__ __launch_bounds__(EDIM) void query_bf16(
        const int* __restrict__ seq, const int* __restrict__ len,
        const float* __restrict__ emb, unsigned short* __restrict__ qbf,
        float* __restrict__ qf) {
    int b = blockIdx.x, d = threadIdx.x;
    int n = len[b];
    float s = 0.f;
    for (int l = 0; l < n; l++)
        s += emb[(size_t)seq[b * HLEN + l] * EDIM + d];
    float q = s / (float)(n > 0 ? n : 1);
    qbf[b * EDIM + d] = f2bf(q);
    qf [b * EDIM + d] = q;
}

// ---- exact top-32 of a batch's candidate buffer: ballot-bisection on keys --
// CAP2 = 256 -> 4 elements per lane (verbatim from the R4-passing kernel).
__device__ inline void compact_batch(float* cv, int* ci, int* cnt, float* thr,
                                     int b, int lane) {
    int n = min(cnt[b], CAP2);
    float val[4]; int idx[4]; unsigned key[4];
    #pragma unroll
    for (int e = 0; e < 4; e++) {
        int i = lane + e * 64;
        if (i < n) {
            float v = cv[b * CAP2 + i];
            unsigned u = __float_as_uint(v);
            key[e] = (u & 0x80000000u) ? ~u : (u | 0x80000000u);
            val[e] = v; idx[e] = ci[b * CAP2 + i];
        } else { key[e] = 0u; val[e] = 0.f; idx[e] = 0; }
    }
    unsigned cur = 0u;                 // max T with count(key >= T) >= 32
    #pragma unroll 1
    for (int bit = 31; bit >= 0; bit--) {
        unsigned mid = cur | (1u << bit);
        int c = 0;
        #pragma unroll
        for (int e = 0; e < 4; e++)
            c += __popcll(__ballot(key[e] >= mid));
        if (c >= NKEEP) cur = mid;
    }
    int base = 0;                      // ballot prefix-sum compaction, no atomics
    #pragma unroll
    for (int e = 0; e < 4; e++) {
        bool keep = key[e] >= cur;
        unsigned long long m = __ballot(keep);
        int p = base + (int)__popcll(m & ((1ull << lane) - 1ull));
        if (keep && p < NKEEP) { cv[b * CAP2 + p] = val[e]; ci[b * CAP2 + p] = idx[e]; }
        base += (int)__popcll(m);
    }
    if (lane == 0) {
        cnt[b] = NKEEP;
        thr[b] = (cur & 0x80000000u) ? __uint_as_float(cur ^ 0x80000000u)
                                     : __uint_as_float(~cur);
    }
}

// ---------------- K2: bf16-MFMA scoring + fused per-range top-32 ------------
// grid = 64 batch-groups x 4 V-ranges = 256 blocks (1/CU, single tranche),
// 768 threads = 12 waves = 3 waves/SIMD (LDS 131.6KB caps at 1 block/CU).
//
// R10 post-mortem (the real bottleneck, finally): VGPR_Count was 76-88 in
// EVERY round since R4 -- but afr alone needs 64 VGPRs. The compiler was
// REMATERIALIZING the loop-invariant A-fragment loads inside the loop:
// every wave-iter issued 20 global loads (16 A + 4 B), all consumed in the
// same iteration, latency fully exposed. Invisible in FETCH_SIZE (qbf is
// L2-resident) and in WRITE_SIZE (remat, not spill). This explains the
// 5727cy/block-iter vs ~1000cy modeled issue, and why all B-prefetch
// experiments (R9/R10) were null: B was only 4 of the 20 loads.
// Fix: pin afr as an opaque asm output after the initial load -- the value
// can no longer be re-loaded from memory, so the allocator must keep it
// resident (~150 VGPR < 170 cap at 3 waves/EU). Semantics-free change.
// Diagnostic: VGPR_Count must jump to ~140-160; if it stays ~76, the pin
// failed and this analysis is wrong.
// (R11 was an infra failure -- "container failed twice" -- identical kernel
// resubmitted; the experiment has not yet run.)
__global__ __launch_bounds__(768, 3) void score_topk(
        const unsigned short* __restrict__ qbf,
        const unsigned short* __restrict__ ebf,
        int* __restrict__ candOut) {
    __shared__ float cv[MT * CAP2];    // 64 KB
    __shared__ int   ci[MT * CAP2];    // 64 KB
    __shared__ int   cnt[MT];
    __shared__ float thr[MT];

    const int tid  = threadIdx.x;
    const int lane = tid & 63;
    const int w    = tid >> 6;                       // wave 0..11
    const int r    = blockIdx.x & (VSPLIT - 1);      // V-range
    const int mg   = blockIdx.x / VSPLIT;            // batch group
    const int b0   = mg * MT;
    const int n15  = lane & 15, quad = lane >> 4;

    const int cstart = (r * NCHUNK_TOT) / VSPLIT;
    const int nch    = ((r + 1) * NCHUNK_TOT) / VSPLIT - cstart;  // 1562/1563

    if (tid < MT) { cnt[tid] = 0; thr[tid] = -INFINITY; }
    __syncthreads();

    // resident A-fragments: 4 msubs x 4 K-steps (64 VGPRs)
    bf16x8 afr[MS][4];
    #pragma unroll
    for (int ms = 0; ms < MS; ms++)
        #pragma unroll
        for (int t = 0; t < 4; t++)
            afr[ms][t] = *(const bf16x8*)(qbf + (b0 + ms * 16 + n15) * EDIM
                                          + t * 32 + quad * 8);
    // PIN: make each fragment an opaque asm output so the compiler cannot
    // rematerialize the load inside the K-loop. Forces true residency.
    #pragma unroll
    for (int ms = 0; ms < MS; ms++)
        #pragma unroll
        for (int t = 0; t < 4; t++)
            asm volatile("" : "+v"(afr[ms][t]));

    float thrR[MS * 4];
    #pragma unroll
    for (int i = 0; i < MS * 4; i++) thrR[i] = -INFINITY;

    const unsigned short* bbase = ebf + ((size_t)cstart * 16 + n15) * EDIM + quad * 8;

    int nextEvt = 1;

    // one iteration: MFMA+insert on `cur`, prefetch chunk(iter+1) into `nxt`
    auto body = [&](int iter, bf16x8 (&cur)[4], bf16x8 (&nxt)[4]) {
        {   // prefetch next iteration's B fragments
            int nit   = (iter + 1 < NITER) ? (iter + 1) : iter;
            int pch   = nit * NWAVE + w;
            int pcc   = (pch < nch) ? pch : (nch - 1);
            const unsigned short* bp = bbase + (size_t)pcc * (16 * EDIM);
            #pragma unroll
            for (int t = 0; t < 4; t++) nxt[t] = *(const bf16x8*)(bp + t * 32);
        }
        f32x4 acc[MS];
        #pragma unroll
        for (int ms = 0; ms < MS; ms++) acc[ms] = (f32x4){0.f, 0.f, 0.f, 0.f};
        #pragma unroll
        for (int t = 0; t < 4; t++)
            #pragma unroll
            for (int ms = 0; ms < MS; ms++)
                acc[ms] = __builtin_amdgcn_mfma_f32_16x16x32_bf16(afr[ms][t], cur[t], acc[ms], 0, 0, 0);

        int chunk = iter * NWAVE + w;
        bool act  = chunk < nch;                     // wave-uniform
        // C/D: item n = lane&15 (col), batch row = quad*4 + reg  [m89/m91]
        if (act) {
            int item = (cstart + chunk) * 16 + n15;
            float s[MS * 4]; bool pass[MS * 4]; bool hit = false;
            #pragma unroll
            for (int k = 0; k < MS * 4; k++) {
                float v = acc[k >> 2][k & 3];
                s[k] = v;
                pass[k] = (v > thrR[k]);
                hit |= pass[k];
            }
            if (__any(hit)) {                        // wave-uniform slow path
                int pz[MS * 4];
                // pass 1: issue all slot-reserving atomics, no waits between
                #pragma unroll
                for (int k = 0; k < MS * 4; k++) {
                    if (pass[k]) {
                        int row = (k >> 2) * 16 + (quad << 2) + (k & 3);
                        pz[k] = atomicAdd(&cnt[row], 1);
                    }
                }
                // keep all atomics above all stores so their latencies overlap
                __builtin_amdgcn_sched_barrier(0);
                // pass 2: one coalesced counted-lgkm wait, then stores
                #pragma unroll
                for (int k = 0; k < MS * 4; k++) {
                    if (pass[k] && pz[k] < CAP2) {
                        int row = (k >> 2) * 16 + (quad << 2) + (k & 3);
                        cv[row * CAP2 + pz[k]] = s[k];
                        ci[row * CAP2 + pz[k]] = item;
                    }
                }
            }
        }
        // static compaction schedule: iters 1,2,4,...,128, and the final iter.
        // Uniform across waves -> barrier counts always match. Trigger cnt>96
        // with CAP2=256: R4-proven headroom.
        if (iter + 1 == nextEvt || iter + 1 == NITER) {
            if (iter + 1 == nextEvt) nextEvt <<= 1;
            bool fin = (iter + 1 == NITER);
            __syncthreads();
            #pragma unroll 1
            for (int b = w; b < MT; b += NWAVE) {    // rows striped over 12 waves
                if (fin || cnt[b] > 96) compact_batch(cv, ci, cnt, thr, b, lane);
            }
            __syncthreads();
            #pragma unroll
            for (int ms = 0; ms < MS; ms++)
                #pragma unroll
                for (int rr = 0; rr < 4; rr++)
                    thrR[ms * 4 + rr] = thr[ms * 16 + (quad << 2) + rr];
        }
    };

    bf16x8 bA[4], bB[4];
    {   // preload iter 0
        int cc0 = (w < nch) ? w : (nch - 1);
        const unsigned short* bp = bbase + (size_t)cc0 * (16 * EDIM);
        #pragma unroll
        for (int t = 0; t < 4; t++) bA[t] = *(const bf16x8*)(bp + t * 32);
    }
    for (int iter = 0; iter < NITER; iter += 2) {    // NITER even: no tail
        body(iter,     bA, bB);
        body(iter + 1, bB, bA);
    }

    // final compact guaranteed cnt==32 per batch; emit candidate indices
    for (int b = w; b < MT; b += NWAVE) {
        if (lane < NKEEP)
            candOut[(b0 + b) * NCAND + r * NKEEP + lane] = ci[b * CAP2 + lane];
    }
}

// ---------------- K3: fp64 rescore of 128 candidates, exact top-21 ----------
__global__ __launch_bounds__(256) void rescore(
        const float* __restrict__ qf, const float* __restrict__ emb,
        const int* __restrict__ cand, float* __restrict__ out) {
    __shared__ double qd[EDIM];
    __shared__ double sv[NCAND];
    __shared__ int    si[NCAND];
    int b = blockIdx.x, t = threadIdx.x;
    if (t < EDIM) qd[t] = (double)qf[b * EDIM + t];  // precomputed in K1
    __syncthreads();

    int c = t >> 1, h = t & 1;                       // 2 threads per candidate
    int idx = cand[b * NCAND + c];
    const float4* ev = (const float4*)(emb + (size_t)idx * EDIM + h * 64);
    double part = 0.0;
    #pragma unroll 4
    for (int j = 0; j < 16; j++) {
        float4 e = ev[j];
        int d = h * 64 + j * 4;
        part += qd[d] * (double)e.x + qd[d + 1] * (double)e.y
              + qd[d + 2] * (double)e.z + qd[d + 3] * (double)e.w;
    }
    part += __shfl_xor(part, 1);                     // combine halves
    if (h == 0) { sv[c] = part; si[c] = idx; }
    __syncthreads();

    if (t < NCAND) {                                 // rank among 128 (ties: low idx)
        double v = sv[t]; int id = si[t];
        int rank = 0;
        for (int j = 0; j < NCAND; j++) {
            double vj = sv[j]; int ij = si[j];
            rank += (vj > v || (vj == v && ij < id)) ? 1 : 0;
        }
        if (rank < TOPK) {
            out[(size_t)b * TOPK + rank] = (float)v;
            out[(size_t)BATCH * TOPK + (size_t)b * TOPK + rank] = (float)id;
        }
    }
}

extern "C" void kernel_launch(void* const* d_in, const int* in_sizes, int n_in,
                              void* d_out, int out_size, void* d_ws, size_t ws_size,
                              hipStream_t stream) {
    const int*   seq = (const int*)d_in[0];
    const int*   len = (const int*)d_in[1];
    const float* emb = (const float*)d_in[2];
    float* out = (float*)d_out;

    // ws: q_bf [4096*128 u16] | emb_bf [100000*128 u16] | cand [4096*128 i32]
    //     | q_f32 [4096*128 f32]   (~30.6 MB total)
    unsigned short* qbf  = (unsigned short*)d_ws;
    unsigned short* ebf  = qbf + (size_t)BATCH * EDIM;
    int*            cand = (int*)(ebf + (size_t)V_ITEMS * EDIM);
    float*          qf   = (float*)(cand + (size_t)BATCH * NCAND);

    conv_bf16 <<<(V_ITEMS * EDIM) / (256 * 8), 256, 0, stream>>>(emb, ebf);
    query_bf16<<<BATCH, EDIM, 0, stream>>>(seq, len, emb, qbf, qf);
    score_topk<<<(BATCH / MT) * VSPLIT, 768, 0, stream>>>(qbf, ebf, cand);
    rescore   <<<BATCH, 256, 0, stream>>>(qf, emb, cand, out);
}